// Round 1
// baseline (171.747 us; speedup 1.0000x reference)
//
#include <hip/hip_runtime.h>
#include <hip/hip_bf16.h>
#include <stdint.h>

// MoE dilated conv FFN: E=8, DM=512, DH=1024, K=3, DIL=2, PAD=2, N=128, L=128.
// Strategy: per-sample GEMMs via bf16 MFMA 16x16x32.
//   K-order kk = k*512 + c  ->  each 32-wide K-chunk is one tap k at channels c0..c0+31.
//   B (activations) staged once per c-chunk as LDS rows l'=l+2 (2 zero pad rows each side);
//   tap k reads row l+2k -> dilation/padding handled purely by LDS row offset.
// All staged tiles are [row][32 k-contig] bf16 (64B rows), XOR-swizzled
// (slot ^= (row>>1)&3) and PRE-SWIZZLED in the workspace so linear
// global_load_lds staging produces the swizzled layout (both-sides rule).

typedef __attribute__((ext_vector_type(8))) short short8;   // 8 bf16 = 4 VGPR
typedef __attribute__((ext_vector_type(4))) float f32x4;

#define NSAMP 128
#define DMV 512
#define DHV 1024

// workspace layout (bytes)
#define OFF_X   0ull                 // x_prep  [128][16][128][4][8] bf16 = 16 MB
#define OFF_H   (16ull << 20)        // h_prep  [128][32][128][4][8] bf16 = 32 MB
#define OFF_W1  (48ull << 20)        // w1_prep [8][16][8][3][128][4][8] bf16 = 24 MB
#define OFF_W2  (72ull << 20)        // w2_prep [8][32][4][3][128][4][8] bf16 = 24 MB
                                     // total 96 MB

__device__ __forceinline__ uint16_t f2bf(float f) {
  uint32_t u = __builtin_bit_cast(uint32_t, f);
  uint32_t r = (u + 0x7FFFu + ((u >> 16) & 1u)) >> 16;  // RTNE
  return (uint16_t)r;
}

__device__ __forceinline__ void async_copy16(const void* g, void* l) {
  __builtin_amdgcn_global_load_lds(
      (const __attribute__((address_space(1))) uint32_t*)g,
      (__attribute__((address_space(3))) uint32_t*)l, 16, 0, 0);
}

__device__ __forceinline__ float gelu_f(float x) {
  // tanh-approx gelu (jax.nn.gelu default). Overflow-safe tanh form.
  float u = 0.7978845608028654f * (x + 0.044715f * x * x * x);
  float t = __expf(2.0f * u);
  float th = 1.0f - 2.0f / (t + 1.0f);
  return 0.5f * x * (1.0f + th);
}

// inp [128][512][128] f32 -> x_prep chunks: chunk(s,cc,l,sub) holds
// c = cc*32 + ((sub ^ f(l+2))&3)*8 + j, value inp[s][c][l].  f(r)=(r>>1)&3.
__global__ void prep_x(const float* __restrict__ inp, uint16_t* __restrict__ xp) {
  uint32_t t = blockIdx.x * 256u + threadIdx.x;   // 1,048,576 chunks
  uint32_t sub = t & 3u;
  uint32_t l = (t >> 2) & 127u;
  uint32_t cc = (t >> 9) & 15u;
  uint32_t s = t >> 13;
  uint32_t fl = ((l + 2u) >> 1) & 3u;
  uint32_t c0 = cc * 32u + ((sub ^ fl) & 3u) * 8u;
  const float* src = inp + ((size_t)s * DMV + c0) * 128u + l;
  uint32_t pk[4];
#pragma unroll
  for (int p = 0; p < 4; ++p) {
    uint32_t lo = f2bf(src[(size_t)(2 * p) * 128u]);
    uint32_t hi = f2bf(src[(size_t)(2 * p + 1) * 128u]);
    pk[p] = lo | (hi << 16);
  }
  uint4 v; v.x = pk[0]; v.y = pk[1]; v.z = pk[2]; v.w = pk[3];
  ((uint4*)xp)[t] = v;
}

// w [E][O][C][3] f32 -> wp [e][cc][mt][k][row][sub][8] bf16, swizzled:
// chunk(row,sub) holds c = cc*32 + ((sub ^ (row>>1))&3)*8 + j at tap k, o = mt*128+row.
__global__ void prep_w(const float* __restrict__ w, uint16_t* __restrict__ wp,
                       int C, int mtBits, int ccBits) {
  uint32_t t = blockIdx.x * 256u + threadIdx.x;   // 1,572,864 chunks
  uint32_t sub = t & 3u;
  uint32_t row = (t >> 2) & 127u;
  uint32_t t2 = t >> 9;
  uint32_t k = t2 % 3u;
  uint32_t t3 = t2 / 3u;
  uint32_t mt = t3 & ((1u << mtBits) - 1u);
  uint32_t t4 = t3 >> mtBits;
  uint32_t cc = t4 & ((1u << ccBits) - 1u);
  uint32_t e = t4 >> ccBits;
  uint32_t O = 128u << mtBits;
  uint32_t o = mt * 128u + row;
  uint32_t c0 = cc * 32u + ((sub ^ (row >> 1)) & 3u) * 8u;
  const float* src = w + (((size_t)e * O + o) * (uint32_t)C + c0) * 3u + k;
  uint32_t pk[4];
#pragma unroll
  for (int p = 0; p < 4; ++p) {
    uint32_t lo = f2bf(src[(size_t)(2 * p) * 3u]);
    uint32_t hi = f2bf(src[(size_t)(2 * p + 1) * 3u]);
    pk[p] = lo | (hi << 16);
  }
  uint4 v; v.x = pk[0]; v.y = pk[1]; v.z = pk[2]; v.w = pk[3];
  ((uint4*)wp)[t] = v;
}

// PHASE 1: x_prep (Cin=512) x w1 -> gelu -> h_prep bf16 (swizzled, conv2-ready)
// PHASE 2: h_prep (Cin=1024) x w2 -> + b2 -> out f32 [s][o][l]
template <int PHASE>
__global__ __launch_bounds__(256, 3) void conv_mfma(
    const uint16_t* __restrict__ bprep, const uint16_t* __restrict__ wprep,
    const float* __restrict__ bias, const int* __restrict__ cnt,
    uint16_t* __restrict__ hout, float* __restrict__ fout) {
  constexpr int CC = (PHASE == 1) ? 16 : 32;   // Cin/32
  constexpr int MT = (PHASE == 1) ? 8 : 4;     // Cout/128
  constexpr int OO = (PHASE == 1) ? DHV : DMV;

  const int s = blockIdx.x;
  const int mt = blockIdx.y;
  int e = 0;
  {
    int cum = cnt[0];
    while (s >= cum && e < 7) { ++e; cum += cnt[e]; }
  }
  const int tid = threadIdx.x;
  const int lane = tid & 63;
  const int wv = tid >> 6;          // wave 0..3, 2x2 grid of 64x64 outputs
  const int wr = wv >> 1, wc = wv & 1;
  const int l15 = lane & 15, kg = lane >> 4;

  // A: [0,24576) = 3 taps x [128 o][32 c];  B: [24576,33024) = [132 l'][32 c]
  __shared__ __align__(16) uint8_t lds[33024];

  if (tid < 16) {  // zero pad rows l' = 0,1,130,131 (persist across c-chunks)
    uint32_t rr = (tid < 8) ? (uint32_t)(tid >> 2) : (130u + (uint32_t)((tid - 8) >> 2));
    uint32_t sb = tid & 3u;
    uint4 z = make_uint4(0, 0, 0, 0);
    *(uint4*)(lds + 24576u + rr * 64u + sb * 16u) = z;
  }

  // LDS read offsets (invariant across c-chunks; swizzle slot = kg ^ (row>>1))
  uint32_t aoff[3][4], boff[3][4];
#pragma unroll
  for (int k = 0; k < 3; ++k) {
#pragma unroll
    for (int a = 0; a < 4; ++a) {
      uint32_t row = (uint32_t)(wr * 64 + a * 16 + l15);
      aoff[k][a] = (uint32_t)(k * 8192) + row * 64u + (((uint32_t)kg ^ (row >> 1)) & 3u) * 16u;
    }
#pragma unroll
    for (int b = 0; b < 4; ++b) {
      uint32_t r = (uint32_t)(wc * 64 + b * 16 + l15 + 2 * k);  // l' = l + 2k
      boff[k][b] = 24576u + r * 64u + (((uint32_t)kg ^ (r >> 1)) & 3u) * 16u;
    }
  }

  const uint16_t* wbase = wprep + ((size_t)e * CC * MT + mt) * 12288;  // [e][cc][mt] tiles
  const uint16_t* xbase = bprep + (size_t)s * CC * 4096;               // [s][cc] tiles

  f32x4 acc[4][4] = {};

  for (int cc = 0; cc < CC; ++cc) {
    const uint16_t* wsrc = wbase + (size_t)cc * (MT * 12288);
    const uint16_t* xsrc = xbase + (size_t)cc * 4096;
#pragma unroll
    for (int it = 0; it < 6; ++it) {   // A: 24 KB (3 taps x 8 KB)
      int idx = wv * 6 + it;
      async_copy16(wsrc + idx * 512 + lane * 8, lds + idx * 1024);
    }
#pragma unroll
    for (int it = 0; it < 2; ++it) {   // B: 8 KB into rows 2..129
      int idx = wv * 2 + it;
      async_copy16(xsrc + idx * 512 + lane * 8, lds + 24576 + 128 + idx * 1024);
    }
    __syncthreads();                   // drains vmcnt before barrier
#pragma unroll
    for (int k = 0; k < 3; ++k) {
      short8 af[4], bf[4];
#pragma unroll
      for (int a = 0; a < 4; ++a) af[a] = *(const short8*)(lds + aoff[k][a]);
#pragma unroll
      for (int b = 0; b < 4; ++b) bf[b] = *(const short8*)(lds + boff[k][b]);
#pragma unroll
      for (int a = 0; a < 4; ++a)
#pragma unroll
        for (int b = 0; b < 4; ++b)
          acc[a][b] = __builtin_amdgcn_mfma_f32_16x16x32_bf16(af[a], bf[b], acc[a][b], 0, 0, 0);
    }
    __syncthreads();
  }

  if (PHASE == 1) {
    // bias + gelu + bf16, repack via LDS into h_prep's swizzled chunk layout,
    // then one contiguous 32 KB coalesced copy-out.
#pragma unroll
    for (int a = 0; a < 4; ++a) {
      uint32_t olb = (uint32_t)(wr * 64 + a * 16 + kg * 4);
      float bv0 = bias[(size_t)e * OO + mt * 128 + olb + 0];
      float bv1 = bias[(size_t)e * OO + mt * 128 + olb + 1];
      float bv2 = bias[(size_t)e * OO + mt * 128 + olb + 2];
      float bv3 = bias[(size_t)e * OO + mt * 128 + olb + 3];
      uint32_t q = (uint32_t)(wr * 2 + (a >> 1));
      uint32_t subl = (uint32_t)((a * 2 + (kg >> 1)) & 3);
      uint32_t j0 = (uint32_t)((kg & 1) * 4);
#pragma unroll
      for (int b = 0; b < 4; ++b) {
        int l = wc * 64 + b * 16 + l15;
        uint32_t fl = ((uint32_t)(l + 2) >> 1) & 3u;
        uint32_t addr = q * 8192u + (uint32_t)l * 64u + (subl ^ fl) * 16u + j0 * 2u;
        float v0 = gelu_f(acc[a][b][0] + bv0);
        float v1 = gelu_f(acc[a][b][1] + bv1);
        float v2 = gelu_f(acc[a][b][2] + bv2);
        float v3 = gelu_f(acc[a][b][3] + bv3);
        uint2 pk;
        pk.x = (uint32_t)f2bf(v0) | ((uint32_t)f2bf(v1) << 16);
        pk.y = (uint32_t)f2bf(v2) | ((uint32_t)f2bf(v3) << 16);
        *(uint2*)(lds + addr) = pk;
      }
    }
    __syncthreads();
    uint16_t* dst = hout + ((size_t)s * 32 + mt * 4) * 4096;  // 32 KB contiguous
#pragma unroll
    for (int i = 0; i < 8; ++i) {
      uint32_t cidx = (uint32_t)tid + (uint32_t)i * 256u;
      *(uint4*)(dst + cidx * 8) = *(const uint4*)(lds + cidx * 16);
    }
  } else {
    float* outp = fout + ((size_t)s * DMV + mt * 128) * 128;
#pragma unroll
    for (int a = 0; a < 4; ++a) {
      int olb = wr * 64 + a * 16 + kg * 4;
#pragma unroll
      for (int r = 0; r < 4; ++r) {
        float bv = bias[(size_t)e * OO + mt * 128 + olb + r];
#pragma unroll
        for (int b = 0; b < 4; ++b) {
          int l = wc * 64 + b * 16 + l15;
          outp[(size_t)(olb + r) * 128 + l] = acc[a][b][r] + bv;
        }
      }
    }
  }
}

extern "C" void kernel_launch(void* const* d_in, const int* in_sizes, int n_in,
                              void* d_out, int out_size, void* d_ws, size_t ws_size,
                              hipStream_t stream) {
  const float* inp = (const float*)d_in[0];
  const int* cnt = (const int*)d_in[1];
  const float* w1 = (const float*)d_in[2];
  const float* b1 = (const float*)d_in[3];
  const float* w2 = (const float*)d_in[4];
  const float* b2 = (const float*)d_in[5];
  float* out = (float*)d_out;
  uint8_t* ws = (uint8_t*)d_ws;
  uint16_t* xp = (uint16_t*)(ws + OFF_X);
  uint16_t* hp = (uint16_t*)(ws + OFF_H);
  uint16_t* w1p = (uint16_t*)(ws + OFF_W1);
  uint16_t* w2p = (uint16_t*)(ws + OFF_W2);

  prep_x<<<dim3(4096), dim3(256), 0, stream>>>(inp, xp);
  prep_w<<<dim3(6144), dim3(256), 0, stream>>>(w1, w1p, 512, 3, 4);
  prep_w<<<dim3(6144), dim3(256), 0, stream>>>(w2, w2p, 1024, 2, 5);
  conv_mfma<1><<<dim3(128, 8), dim3(256), 0, stream>>>(xp, w1p, b1, cnt, hp, nullptr);
  conv_mfma<2><<<dim3(128, 4), dim3(256), 0, stream>>>(hp, w2p, b2, cnt, nullptr, out);
}

// Round 2
// 160.816 us; speedup vs baseline: 1.0680x; 1.0680x over previous
//
#include <hip/hip_runtime.h>
#include <hip/hip_bf16.h>
#include <stdint.h>

// MoE dilated conv FFN: E=8, DM=512, DH=1024, K=3, DIL=2, PAD=2, N=128, L=128.
// bf16 MFMA 16x16x32 GEMMs; K-order kk = k*512 + c (tap-major chunks of 32 ch).
// B (activations) staged per c-chunk as LDS rows l'=l+2 with 2 zero pad rows each
// side; tap k reads row l+2k -> dilation/padding is a pure LDS row offset, and ONE
// B tile serves all 3 taps.
// This round: 2-sample blocks (per-expert counts are even -> pairs never straddle
// experts), 8 waves, double-buffered LDS with the T3-minimal schedule (stage next
// chunk first, one barrier per chunk), chunked XCD swizzle for weight L2 locality.
// All staged tiles [row][32ch] (64B rows), XOR-swizzled (slot ^= (row>>1)&3) and
// PRE-SWIZZLED in workspace so linear global_load_lds yields the swizzled layout.

typedef __attribute__((ext_vector_type(8))) short short8;   // 8 bf16 = 4 VGPR
typedef __attribute__((ext_vector_type(4))) float f32x4;

#define NSAMP 128
#define DMV 512
#define DHV 1024

// workspace layout (bytes)
#define OFF_X   0ull                 // x_prep  [128][16][128][4][8] bf16 = 16 MB
#define OFF_H   (16ull << 20)        // h_prep  [128][32][128][4][8] bf16 = 32 MB
#define OFF_W1  (48ull << 20)        // w1_prep [8][16][8][3][128][4][8] bf16 = 24 MB
#define OFF_W2  (72ull << 20)        // w2_prep [8][32][4][3][128][4][8] bf16 = 24 MB

__device__ __forceinline__ uint16_t f2bf(float f) {
  uint32_t u = __builtin_bit_cast(uint32_t, f);
  uint32_t r = (u + 0x7FFFu + ((u >> 16) & 1u)) >> 16;  // RTNE
  return (uint16_t)r;
}

__device__ __forceinline__ void async_copy16(const void* g, void* l) {
  __builtin_amdgcn_global_load_lds(
      (const __attribute__((address_space(1))) uint32_t*)g,
      (__attribute__((address_space(3))) uint32_t*)l, 16, 0, 0);
}

__device__ __forceinline__ float gelu_f(float x) {
  float u = 0.7978845608028654f * (x + 0.044715f * x * x * x);
  float t = __expf(2.0f * u);
  float th = 1.0f - 2.0f / (t + 1.0f);
  return 0.5f * x * (1.0f + th);
}

// inp [128][512][128] f32 -> x_prep chunks: chunk(s,cc,l,sub) holds
// c = cc*32 + ((sub ^ f(l+2))&3)*8 + j, value inp[s][c][l].  f(r)=(r>>1)&3.
__global__ void prep_x(const float* __restrict__ inp, uint16_t* __restrict__ xp) {
  uint32_t t = blockIdx.x * 256u + threadIdx.x;
  uint32_t sub = t & 3u;
  uint32_t l = (t >> 2) & 127u;
  uint32_t cc = (t >> 9) & 15u;
  uint32_t s = t >> 13;
  uint32_t fl = ((l + 2u) >> 1) & 3u;
  uint32_t c0 = cc * 32u + ((sub ^ fl) & 3u) * 8u;
  const float* src = inp + ((size_t)s * DMV + c0) * 128u + l;
  uint32_t pk[4];
#pragma unroll
  for (int p = 0; p < 4; ++p) {
    uint32_t lo = f2bf(src[(size_t)(2 * p) * 128u]);
    uint32_t hi = f2bf(src[(size_t)(2 * p + 1) * 128u]);
    pk[p] = lo | (hi << 16);
  }
  uint4 v; v.x = pk[0]; v.y = pk[1]; v.z = pk[2]; v.w = pk[3];
  ((uint4*)xp)[t] = v;
}

// w [E][O][C][3] f32 -> wp [e][cc][mt][k][row][sub][8] bf16, swizzled.
__global__ void prep_w(const float* __restrict__ w, uint16_t* __restrict__ wp,
                       int C, int mtBits, int ccBits) {
  uint32_t t = blockIdx.x * 256u + threadIdx.x;
  uint32_t sub = t & 3u;
  uint32_t row = (t >> 2) & 127u;
  uint32_t t2 = t >> 9;
  uint32_t k = t2 % 3u;
  uint32_t t3 = t2 / 3u;
  uint32_t mt = t3 & ((1u << mtBits) - 1u);
  uint32_t t4 = t3 >> mtBits;
  uint32_t cc = t4 & ((1u << ccBits) - 1u);
  uint32_t e = t4 >> ccBits;
  uint32_t O = 128u << mtBits;
  uint32_t o = mt * 128u + row;
  uint32_t c0 = cc * 32u + ((sub ^ (row >> 1)) & 3u) * 8u;
  const float* src = w + (((size_t)e * O + o) * (uint32_t)C + c0) * 3u + k;
  uint32_t pk[4];
#pragma unroll
  for (int p = 0; p < 4; ++p) {
    uint32_t lo = f2bf(src[(size_t)(2 * p) * 3u]);
    uint32_t hi = f2bf(src[(size_t)(2 * p + 1) * 3u]);
    pk[p] = lo | (hi << 16);
  }
  uint4 v; v.x = pk[0]; v.y = pk[1]; v.z = pk[2]; v.w = pk[3];
  ((uint4*)wp)[t] = v;
}

// PHASE 1: 256x256 tile (M=256 of DH, N=2 samples x 128), CC=16 chunks.
// PHASE 2: 128x256 tile (M=128 of DM),                   CC=32 chunks.
// 8 waves as 2x4: wave rows = wr*(AREP*16), wave cols = wc*64 (sample wc>>1).
template <int PHASE>
__global__ __launch_bounds__(512, 2) void conv_mfma(
    const uint16_t* __restrict__ bprep, const uint16_t* __restrict__ wprep,
    const float* __restrict__ bias, const int* __restrict__ cnt,
    uint16_t* __restrict__ hout, float* __restrict__ fout) {
  constexpr int CC = (PHASE == 1) ? 16 : 32;        // Cin/32
  constexpr int HALVES = (PHASE == 1) ? 2 : 1;      // 128-row prep tiles per block
  constexpr int MTP = (PHASE == 1) ? 8 : 4;         // prep mt tile count
  constexpr int AREP = 4 * HALVES;                  // A fragments per wave
  constexpr int OO = (PHASE == 1) ? DHV : DMV;
  constexpr uint32_t AS = HALVES * 24576u;          // A bytes per buffer
  constexpr uint32_t BUFS = AS + 16896u;            // + B: 2 samples x 132 x 64B

  // chunked XCD swizzle: hardware blocks b%8==x (XCD x) take works x*32..x*32+31
  uint32_t b = blockIdx.x;
  uint32_t work = (b & 7u) * 32u + (b >> 3);
  const int pr = work & 63;          // sample pair: samples 2pr, 2pr+1
  const int mt = work >> 6;          // output tile
  int e = 0;
  {
    int cum = cnt[0];
    while (2 * pr >= cum && e < 7) { ++e; cum += cnt[e]; }
  }
  const int tid = threadIdx.x;
  const int lane = tid & 63;
  const int wv = tid >> 6;
  const int wr = wv >> 2, wc = wv & 3;
  const int l15 = lane & 15, kg = lane >> 4;

  __shared__ __align__(16) uint8_t lds[2 * BUFS];

  // invariant LDS read offsets
  uint32_t aOff[AREP];
#pragma unroll
  for (int a = 0; a < AREP; ++a) {
    uint32_t R = (uint32_t)(wr * (AREP * 16) + a * 16 + l15);
    uint32_t h = R >> 7, ri = R & 127u;
    aOff[a] = h * 24576u + ri * 64u + (((uint32_t)kg ^ (ri >> 1)) & 3u) * 16u;
  }
  uint32_t lB[4];
#pragma unroll
  for (int bq = 0; bq < 4; ++bq) lB[bq] = (uint32_t)((wc & 1) * 64 + bq * 16 + l15);
  const uint32_t pOff = AS + (uint32_t)(wc >> 1) * 8448u;
  const int mtBase = (PHASE == 1) ? mt * 2 : mt;

  auto STAGE = [&](int buf, int cc) {
    uint8_t* bb = lds + (uint32_t)buf * BUFS;
    const uint16_t* wsrc = wprep + (((size_t)e * CC + cc) * MTP + mtBase) * 12288;
#pragma unroll
    for (int i = 0; i < 3 * HALVES; ++i)            // A: (h*3+k)*4096 src == i*8192 dst
      async_copy16(wsrc + i * 4096 + tid * 8, bb + (uint32_t)i * 8192u + tid * 16);
#pragma unroll
    for (int p = 0; p < 2; ++p)                     // B: rows 2..129 per sample
      async_copy16(bprep + (((size_t)(2 * pr + p)) * CC + cc) * 4096 + tid * 8,
                   bb + AS + (uint32_t)p * 8448u + 128u + tid * 16);
  };

  // zero pad rows l' = 0,1,130,131 (both buffers, both samples) — persist
  if (tid < 64) {
    uint32_t n = (uint32_t)tid >> 5, rest = (uint32_t)tid & 31u;
    uint32_t p = rest >> 4, ri = (rest >> 2) & 3u, sb = rest & 3u;
    uint32_t rowByte = (ri < 2) ? ri * 64u : (8320u + (ri - 2) * 64u);
    uint4 z = make_uint4(0, 0, 0, 0);
    *(uint4*)(lds + n * BUFS + AS + p * 8448u + rowByte + sb * 16u) = z;
  }
  STAGE(0, 0);
  __syncthreads();

  f32x4 acc[AREP][4] = {};

#pragma unroll 2
  for (int cc = 0; cc < CC; ++cc) {
    int cur = cc & 1;
    if (cc + 1 < CC) STAGE(cur ^ 1, cc + 1);        // prefetch next chunk
    const uint8_t* bb = lds + (uint32_t)cur * BUFS;
#pragma unroll
    for (int k = 0; k < 3; ++k) {
      short8 af[AREP], bf[4];
#pragma unroll
      for (int a = 0; a < AREP; ++a)
        af[a] = *(const short8*)(bb + aOff[a] + (uint32_t)k * 8192u);
#pragma unroll
      for (int bq = 0; bq < 4; ++bq) {
        uint32_t r = lB[bq] + 2u * (uint32_t)k;     // l' = l + 2k
        bf[bq] = *(const short8*)(bb + pOff + r * 64u +
                                  (((uint32_t)kg ^ (r >> 1)) & 3u) * 16u);
      }
#pragma unroll
      for (int a = 0; a < AREP; ++a)
#pragma unroll
        for (int bq = 0; bq < 4; ++bq)
          acc[a][bq] = __builtin_amdgcn_mfma_f32_16x16x32_bf16(af[a], bf[bq], acc[a][bq], 0, 0, 0);
    }
    __syncthreads();                                // one barrier per chunk (drains vm+lgkm)
  }

  const int p = wc >> 1;
  const int s = 2 * pr + p;
  if (PHASE == 1) {
    // bias + gelu + bf16, write directly in h_prep's swizzled chunk layout
#pragma unroll
    for (int a = 0; a < AREP; ++a) {
      int ob = mt * 256 + wr * 128 + a * 16 + kg * 4;
      float4 bv = *(const float4*)(bias + (size_t)e * OO + ob);
      int cc2 = mt * 8 + wr * 4 + (a >> 1);
      uint32_t g = (uint32_t)((a & 1) * 2 + (kg >> 1));
      uint32_t j0 = (uint32_t)((kg & 1) * 4);
#pragma unroll
      for (int bq = 0; bq < 4; ++bq) {
        int l = (wc & 1) * 64 + bq * 16 + l15;
        uint32_t flq = ((uint32_t)(l + 2) >> 1) & 3u;
        uint32_t sub = g ^ flq;
        float v0 = gelu_f(acc[a][bq][0] + bv.x);
        float v1 = gelu_f(acc[a][bq][1] + bv.y);
        float v2 = gelu_f(acc[a][bq][2] + bv.z);
        float v3 = gelu_f(acc[a][bq][3] + bv.w);
        uint2 pk;
        pk.x = (uint32_t)f2bf(v0) | ((uint32_t)f2bf(v1) << 16);
        pk.y = (uint32_t)f2bf(v2) | ((uint32_t)f2bf(v3) << 16);
        size_t ci = ((size_t)s * 32 + cc2) * 128 + l;
        *(uint2*)(hout + ci * 32 + sub * 8 + j0) = pk;
      }
    }
  } else {
#pragma unroll
    for (int a = 0; a < AREP; ++a) {
      int ob = mt * 128 + wr * 64 + a * 16 + kg * 4;
      float4 bv = *(const float4*)(bias + (size_t)e * OO + ob);
      float bvr[4] = {bv.x, bv.y, bv.z, bv.w};
      float* op = fout + ((size_t)s * DMV + ob) * 128;
#pragma unroll
      for (int bq = 0; bq < 4; ++bq) {
        int l = (wc & 1) * 64 + bq * 16 + l15;
#pragma unroll
        for (int r = 0; r < 4; ++r)
          op[(size_t)r * 128 + l] = acc[a][bq][r] + bvr[r];
      }
    }
  }
}

extern "C" void kernel_launch(void* const* d_in, const int* in_sizes, int n_in,
                              void* d_out, int out_size, void* d_ws, size_t ws_size,
                              hipStream_t stream) {
  const float* inp = (const float*)d_in[0];
  const int* cnt = (const int*)d_in[1];
  const float* w1 = (const float*)d_in[2];
  const float* b1 = (const float*)d_in[3];
  const float* w2 = (const float*)d_in[4];
  const float* b2 = (const float*)d_in[5];
  float* out = (float*)d_out;
  uint8_t* ws = (uint8_t*)d_ws;
  uint16_t* xp = (uint16_t*)(ws + OFF_X);
  uint16_t* hp = (uint16_t*)(ws + OFF_H);
  uint16_t* w1p = (uint16_t*)(ws + OFF_W1);
  uint16_t* w2p = (uint16_t*)(ws + OFF_W2);

  prep_x<<<dim3(4096), dim3(256), 0, stream>>>(inp, xp);
  prep_w<<<dim3(6144), dim3(256), 0, stream>>>(w1, w1p, 512, 3, 4);
  prep_w<<<dim3(6144), dim3(256), 0, stream>>>(w2, w2p, 1024, 2, 5);
  conv_mfma<1><<<dim3(256), dim3(512), 0, stream>>>(xp, w1p, b1, cnt, hp, nullptr);
  conv_mfma<2><<<dim3(256), dim3(512), 0, stream>>>(hp, w2p, b2, cnt, nullptr, out);
}